// Round 2
// baseline (567.875 us; speedup 1.0000x reference)
//
#include <hip/hip_runtime.h>
#include <hip/hip_bf16.h>

// Problem constants
#define B_    8
#define C_    32
#define O_    64
#define GIN   33
#define GOUT  15
#define GF    7
#define XDIM  64
#define KK    5
#define XOUT  60
#define CCH   224      // C_*GF  (GEMM K per tap)
#define TAPS  25
#define NCHNK 7        // CCH/32 channel chunks
#define TILE_ROWS 4
#define TILE_POS  240  // TILE_ROWS*60
#define NFRAGS 15      // TILE_POS/16

typedef __attribute__((ext_vector_type(8))) __bf16 bf16x8;
typedef __attribute__((ext_vector_type(8))) unsigned short u16x8;
typedef __attribute__((ext_vector_type(4))) float f32x4;

__device__ __forceinline__ f32x4 mfma16(u16x8 a, u16x8 b, f32x4 c) {
  return __builtin_amdgcn_mfma_f32_16x16x32_bf16(
      __builtin_bit_cast(bf16x8, a), __builtin_bit_cast(bf16x8, b), c, 0, 0, 0);
}

// Weights: w[o][c][f][kh][kw] f32  ->  wt[tap][ck][o][c8] bf16
// (cc = ck*32 + c8 = c*7 + f;  tap = kh*5+kw)
// Each A fragment (64 lanes x 16B) is then one contiguous 1KB block.
__global__ void wt_kernel(const float* __restrict__ w, unsigned short* __restrict__ wt) {
  int i = blockIdx.x * 256 + threadIdx.x;
  if (i >= TAPS * NCHNK * O_ * 32) return;
  int c8  = i & 31;
  int o   = (i >> 5) & 63;
  int ck  = (i >> 11) % NCHNK;
  int tap = i / (NCHNK * O_ * 32);
  int cc = ck * 32 + c8;
  int c = cc / GF, f = cc % GF;
  float v = w[(size_t)o * (C_ * GF * KK * KK) + c * (GF * KK * KK) + f * (KK * KK) + tap];
  __bf16 hb = (__bf16)v;
  wt[i] = __builtin_bit_cast(unsigned short, hb);
}

// LDS layout: Xs[pos*32 + 8*slot + (cc&7)], slot = (cc>>3) ^ ((pos>>1)&3)
// pos = row*64 + col (8 rows x 64 cols), 32 channels per chunk. 32KB.
// - staging b128 writes (8 ch/thread/pos): 8 consecutive pos cover all 32 banks once -> conflict-free
// - frag b128 reads: slot over 8 consecutive pos = {0,4,1,5,2,6,3,7} -> conflict-free
__global__ void __launch_bounds__(256, 3)
conv_kernel(const float* __restrict__ x, const unsigned short* __restrict__ wt,
            const float* __restrict__ bias, const int* __restrict__ idx,
            float* __restrict__ out) {
  __shared__ __align__(16) unsigned short Xs[512 * 32];  // 32 KB
  __shared__ int   sImg[CCH];
  __shared__ float sBias[O_];

  const int bid  = blockIdx.x;
  const int tile = bid % 15;
  const int g    = (bid / 15) % GOUT;
  const int b    = bid / (15 * GOUT);

  const int tid  = threadIdx.x;
  const int lane = tid & 63;
  const int wv   = tid >> 6;    // wave id 0..3 (also staging slot-group q)
  const int lo   = lane & 15;
  const int lk   = lane >> 4;   // 0..3

  if (tid < CCH) {
    int c = tid / GF, f = tid % GF;
    int gin = idx[g * GF + f];
    sImg[tid] = ((b * C_ + c) * GIN + gin) * (XDIM * XDIM);
  }
  if (tid < O_) sBias[tid] = bias[tid];

  // Per-lane input-position base (ph*64+pw) for this wave's n-frags.
  int p0[4];
  int nvalid = 0;
#pragma unroll
  for (int i = 0; i < 4; ++i) {
    int nf = wv * 4 + i;
    if (nf < NFRAGS) {
      int p  = nf * 16 + lo;        // 0..239
      int ph = p / 60, pw = p - ph * 60;
      p0[i] = ph * 64 + pw;
      nvalid = i + 1;
    }
  }

  f32x4 acc[4][4];
#pragma unroll
  for (int m = 0; m < 4; ++m)
#pragma unroll
    for (int i = 0; i < 4; ++i) acc[m][i] = f32x4{0.f, 0.f, 0.f, 0.f};

  const int r0  = tile * TILE_ROWS;  // first staged input row
  const int col = tid & 63;

  for (int ck = 0; ck < NCHNK; ++ck) {
    const int c0 = ck * 32;
    __syncthreads();  // Xs free to overwrite (covers sImg/sBias init on first pass)

    // ---- stage: each thread writes 8 channels x 8 rows at its col ----
#pragma unroll
    for (int row = 0; row < 8; ++row) {
      int ga = (r0 + row) * XDIM + col;
      float v[8];
#pragma unroll
      for (int k = 0; k < 8; ++k) v[k] = x[sImg[c0 + 8 * wv + k] + ga];
      u16x8 pk;
#pragma unroll
      for (int k = 0; k < 8; ++k)
        pk[k] = __builtin_bit_cast(unsigned short, (__bf16)v[k]);
      int pos = row * 64 + col;
      *reinterpret_cast<u16x8*>(&Xs[pos * 32 + 8 * (wv ^ ((pos >> 1) & 3))]) = pk;
    }
    __syncthreads();

    // ---- 25 taps fully unrolled: 4 A-frags (global, contiguous), <=4 B-frags (LDS), 16 MFMA ----
#pragma unroll
    for (int kh = 0; kh < 5; ++kh) {
#pragma unroll
      for (int kw = 0; kw < 5; ++kw) {
        const int tap = kh * 5 + kw;
        const unsigned short* wbase = wt + ((size_t)(tap * NCHNK + ck) << 11);
        u16x8 a[4], bf[4];
#pragma unroll
        for (int m = 0; m < 4; ++m)
          a[m] = *reinterpret_cast<const u16x8*>(wbase + ((m * 16 + lo) << 5) + (lk << 3));
#pragma unroll
        for (int i = 0; i < 4; ++i)
          if (i < nvalid) {
            int pt = p0[i] + kh * 64 + kw;
            bf[i] = *reinterpret_cast<const u16x8*>(
                &Xs[pt * 32 + 8 * (lk ^ ((pt >> 1) & 3))]);
          }
#pragma unroll
        for (int i = 0; i < 4; ++i)
          if (i < nvalid)
#pragma unroll
            for (int m = 0; m < 4; ++m)
              acc[m][i] = mfma16(a[m], bf[i], acc[m][i]);
      }
    }
  }

  // ---- epilogue: acc + bias -> out[b][o][g][ph][pw] (f32) ----
  const size_t obase = ((size_t)b * O_ * GOUT + g) * 3600 + (size_t)tile * TILE_POS;
#pragma unroll
  for (int m = 0; m < 4; ++m) {
#pragma unroll
    for (int i = 0; i < 4; ++i) {
      if (i < nvalid) {
        int nf = wv * 4 + i;
        int p  = nf * 16 + lo;
#pragma unroll
        for (int v = 0; v < 4; ++v) {
          int o = m * 16 + 4 * lk + v;
          out[obase + (size_t)o * (GOUT * 3600) + p] = acc[m][i][v] + sBias[o];
        }
      }
    }
  }
}

extern "C" void kernel_launch(void* const* d_in, const int* in_sizes, int n_in,
                              void* d_out, int out_size, void* d_ws, size_t ws_size,
                              hipStream_t stream) {
  const float* x      = (const float*)d_in[0];
  const float* weight = (const float*)d_in[1];
  const float* bias   = (const float*)d_in[2];
  const int*   idx    = (const int*)d_in[3];
  float* out = (float*)d_out;
  unsigned short* wt = (unsigned short*)d_ws;  // 25*7*64*32*2 = 716800 B

  wt_kernel<<<(TAPS * NCHNK * O_ * 32 + 255) / 256, 256, 0, stream>>>(weight, wt);
  conv_kernel<<<B_ * GOUT * 15, 256, 0, stream>>>(x, wt, bias, idx, out);
}

// Round 3
// 330.595 us; speedup vs baseline: 1.7177x; 1.7177x over previous
//
#include <hip/hip_runtime.h>
#include <hip/hip_bf16.h>

// ---- problem constants ----
#define B_    8
#define GOUT  15
#define GF    7
#define TAPS  25
#define CCH   224        // 32*7 GEMM-K channels
#define NCHNK 7          // 224/32
#define NTILE 10         // 10 tiles of 6 output rows (exact: 60 = 10*6)
#define TROWS 6          // output rows per tile
#define SROWS 10         // staged input rows (6 + 4 halo)
#define NPOS  360        // positions per tile (6*60)
#define NF_   23         // ceil(360/16) position fragments (last has 8 valid)

typedef __attribute__((ext_vector_type(8))) __bf16 bf16x8;
typedef __attribute__((ext_vector_type(8))) unsigned short u16x8;
typedef __attribute__((ext_vector_type(4))) float f32x4;

__device__ __forceinline__ f32x4 mfma16(u16x8 a, u16x8 b, f32x4 c) {
  return __builtin_amdgcn_mfma_f32_16x16x32_bf16(
      __builtin_bit_cast(bf16x8, a), __builtin_bit_cast(bf16x8, b), c, 0, 0, 0);
}

// Weights: w[o][c][f][kh][kw] f32 -> wt[tap][ck][o][s][e] bf16 (4KB per (tap,ck))
// Stored channel at slot s: cc = ck*32 + 8*(s ^ ((o>>1)&3)) + e   (bank swizzle
// baked in so the in-kernel A-frag ds_read at slot = lk ^ ((lo>>1)&3) is 2-way max)
__global__ void wt_kernel(const float* __restrict__ w, unsigned short* __restrict__ wt) {
  int i = blockIdx.x * 256 + threadIdx.x;
  if (i >= TAPS * NCHNK * 64 * 32) return;
  int e   = i & 7;
  int s   = (i >> 3) & 3;
  int o   = (i >> 5) & 63;
  int ck  = (i >> 11) % NCHNK;
  int tap = i / (NCHNK * 64 * 32);
  int cc = ck * 32 + 8 * (s ^ ((o >> 1) & 3)) + e;
  int c = cc / GF, f = cc - GF * (cc / GF);
  float v = w[(size_t)o * (32 * GF * TAPS) + c * (GF * TAPS) + f * TAPS + tap];
  __bf16 hb = (__bf16)v;
  wt[i] = __builtin_bit_cast(unsigned short, hb);
}

// Block = (b, g, tile of 6 out rows). 4 waves; wave: 4 m-frags (64 o) x <=6 n-frags.
// LDS: Xs = 10 rows x 64 cols x 32 ch bf16 (40KB, XOR-swizzled);
//      Ws = 5 taps x 64 o x 32 ch bf16 (20KB, single-buffered per kh-group,
//           refilled via T14 reg-prefetch: global->VGPR during compute, ds_write after barrier)
__global__ void __launch_bounds__(256, 2)
conv_kernel(const float* __restrict__ x, const unsigned short* __restrict__ wt,
            const float* __restrict__ bias, const int* __restrict__ idx,
            float* __restrict__ out) {
  __shared__ __align__(16) unsigned short Xs[640 * 32];  // 40 KB
  __shared__ __align__(16) unsigned short Ws[5 * 2048];  // 20 KB
  __shared__ float sBias[64];

  const int bid  = blockIdx.x;
  const int tile = bid % NTILE;
  const int g    = (bid / NTILE) % GOUT;
  const int b    = bid / (NTILE * GOUT);

  const int tid  = threadIdx.x;
  const int lane = tid & 63;
  const int wv   = tid >> 6;   // wave id 0..3 = staging channel-group q
  const int lo   = lane & 15;
  const int lk   = lane >> 4;
  const int col  = tid & 63;

  if (tid < 64) sBias[tid] = bias[tid];

  // Strided frag assignment nf = wv + 4*i  -> balanced (6,6,6,5)
  int p0[6];
  int pvalid = 0;
#pragma unroll
  for (int i = 0; i < 6; ++i) {
    int nf = wv + 4 * i;
    p0[i] = 0;
    if (nf < NF_) {
      int p = nf * 16 + lo;
      int pc = (p < NPOS) ? p : 0;          // clamp invalid lanes (epilogue-guarded)
      p0[i] = (pc / 60) * 64 + (pc - 60 * (pc / 60));
      pvalid = i + 1;
    }
  }

  f32x4 acc[4][6];
#pragma unroll
  for (int m = 0; m < 4; ++m)
#pragma unroll
    for (int i = 0; i < 6; ++i) acc[m][i] = f32x4{0.f, 0.f, 0.f, 0.f};

  // W-group register prefetch (T14): 5 x 16B per thread
  const unsigned short* wsrc = wt + tid * 8;
  u16x8 wr[5];
  auto wprefetch = [&](int grp) {  // grp = ck*5 + kh
    int ckp = grp / 5, kh = grp - 5 * (grp / 5);
#pragma unroll
    for (int t = 0; t < 5; ++t)
      wr[t] = *reinterpret_cast<const u16x8*>(wsrc + ((kh * 5 + t) * NCHNK + ckp) * 2048);
  };

  wprefetch(0);
  const int r0 = tile * TROWS;

  for (int ck = 0; ck < NCHNK; ++ck) {
    const int c0 = ck * 32;
    // image base offsets for this wave's 8 channels (wave-uniform -> SALU)
    int ib[8];
#pragma unroll
    for (int k = 0; k < 8; ++k) {
      int cc = c0 + 8 * wv + k;
      int c = cc / GF, f = cc - GF * c;
      int gin = idx[g * GF + f];
      ib[k] = ((b * 32 + c) * 33 + gin) * 4096;
    }

    __syncthreads();  // all waves done reading previous chunk's Xs / Ws
    // commit W group (ck, kh=0) from regs, then prefetch (ck, kh=1)
#pragma unroll
    for (int t = 0; t < 5; ++t)
      *reinterpret_cast<u16x8*>(&Ws[t * 2048 + tid * 8]) = wr[t];
    wprefetch(ck * 5 + 1);

    // stage x chunk: 10 rows x 64 cols, 8 channels per thread, bf16-packed
#pragma unroll
    for (int row = 0; row < SROWS; ++row) {
      int ga = (r0 + row) * 64 + col;
      u16x8 pk;
#pragma unroll
      for (int k = 0; k < 8; ++k) {
        float v = x[ib[k] + ga];
        pk[k] = __builtin_bit_cast(unsigned short, (__bf16)v);
      }
      int pos = row * 64 + col;
      *reinterpret_cast<u16x8*>(&Xs[pos * 32 + 8 * (wv ^ ((pos >> 1) & 3))]) = pk;
    }
    __syncthreads();  // Xs + Ws[group kh=0] ready

    for (int kh = 0; kh < 5; ++kh) {
      if (kh > 0) {
        __syncthreads();  // done reading previous group
#pragma unroll
        for (int t = 0; t < 5; ++t)
          *reinterpret_cast<u16x8*>(&Ws[t * 2048 + tid * 8]) = wr[t];
        int g2 = ck * 5 + kh + 1;
        if (g2 < 35) wprefetch(g2);
        __syncthreads();  // new group visible
      }
#pragma unroll
      for (int kw = 0; kw < 5; ++kw) {
        u16x8 a[4], bfr[6];
#pragma unroll
        for (int m = 0; m < 4; ++m)
          a[m] = *reinterpret_cast<const u16x8*>(
              &Ws[kw * 2048 + (m * 16 + lo) * 32 + 8 * (lk ^ ((lo >> 1) & 3))]);
#pragma unroll
        for (int i = 0; i < 6; ++i)
          if (i < pvalid) {
            int pt = p0[i] + kh * 64 + kw;
            bfr[i] = *reinterpret_cast<const u16x8*>(
                &Xs[pt * 32 + 8 * (lk ^ ((pt >> 1) & 3))]);
          }
#pragma unroll
        for (int i = 0; i < 6; ++i)
          if (i < pvalid)
#pragma unroll
            for (int m = 0; m < 4; ++m)
              acc[m][i] = mfma16(a[m], bfr[i], acc[m][i]);
      }
    }
  }

  // epilogue: out[((b*64+o)*15+g)*3600 + tile*360 + p], p = nf*16+lo < 360
#pragma unroll
  for (int i = 0; i < 6; ++i) {
    if (i < pvalid) {
      int nf = wv + 4 * i;
      int p  = nf * 16 + lo;
      if (p < NPOS) {
        const size_t pb = (size_t)tile * NPOS + p;
#pragma unroll
        for (int m = 0; m < 4; ++m)
#pragma unroll
          for (int v = 0; v < 4; ++v) {
            int o = m * 16 + 4 * lk + v;
            out[(size_t)(b * 960 + o * 15 + g) * 3600 + pb] = acc[m][i][v] + sBias[o];
          }
      }
    }
  }
}

extern "C" void kernel_launch(void* const* d_in, const int* in_sizes, int n_in,
                              void* d_out, int out_size, void* d_ws, size_t ws_size,
                              hipStream_t stream) {
  const float* x      = (const float*)d_in[0];
  const float* weight = (const float*)d_in[1];
  const float* bias   = (const float*)d_in[2];
  const int*   idx    = (const int*)d_in[3];
  float* out = (float*)d_out;
  unsigned short* wt = (unsigned short*)d_ws;  // 25*7*64*32*2 = 716800 B

  wt_kernel<<<(TAPS * NCHNK * 64 * 32 + 255) / 256, 256, 0, stream>>>(weight, wt);
  conv_kernel<<<B_ * GOUT * NTILE, 256, 0, stream>>>(x, wt, bias, idx, out);
}